// Round 3
// baseline (229460.547 us; speedup 1.0000x reference)
//
#include <hip/hip_runtime.h>
#include <cmath>

// Quantum bilinear controller solver (N=64, K=8, NT=1000, N_its=2), fp32.
// Sequential sweeps run as single-workgroup kernels (256 threads) with all
// 64x64 state in LDS; history (Ps, Pk1, trajectories) lives in d_ws.

#define NTS 1000
#define DT  0.02f
#define LDM 68          // padded leading dim for 64-col LDS matrices (bank spread, 16B-aligned rows)

// ---------------- workspace layout (floats) ----------------
constexpr int O_PS   = 0;                       // (NTS+1) x 64 x 64
constexpr int O_PK1  = O_PS  + (NTS+1)*4096;    // NTS x 64 x 64
constexpr int O_XG   = O_PK1 + NTS*4096;        // NTS x 64   (iteration-1 trajectory)
constexpr int O_XK1  = O_XG  + NTS*64;          // NTS x 64
constexpr int O_H1   = O_XK1 + NTS*64;          // H1[j][l][n] = H[j][n][l]   (64x8x64)
constexpr int O_H2   = O_H1  + 64*8*64;         // H2[j][s][m] = H[m][j][s]   (64x8x64)
constexpr int O_RI   = O_H2  + 64*8*64;         // Ri (8x8)
constexpr int O_BRI  = O_RI  + 64;              // B@Ri    (64x8)
constexpr int O_RIBT = O_BRI + 512;             // Ri@B^T  (8x64)
constexpr int O_BT   = O_RIBT+ 512;             // B^T     (8x64)
constexpr int WS_FLOATS = O_BT + 512;           // ~8.39M floats = 33.6 MB

// ---------------- output layout (floats) ----------------
constexpr int O_X0o = 0;        // x_res[0]  (1000x64)
constexpr int O_X1o = 64000;    // x_res[1]
constexpr int O_X2o = 128000;   // x_res[2]
constexpr int O_U0o = 192000;   // u_res[0] (zeros)
constexpr int O_U1o = 200000;   // u_res[1]
constexpr int O_U2o = 208000;   // u_res[2]

// elementwise pass over a 64x64 padded LDS matrix with 256 threads
#define EW_FOR(I, J, IJ, ...) do { \
  const int _r = (int)threadIdx.x >> 2; const int _c0 = ((int)threadIdx.x & 3) << 4; \
  _Pragma("unroll") \
  for (int _e = 0; _e < 16; ++_e) { const int I = _r; const int J = _c0 + _e; const int IJ = (I)*LDM + (J); __VA_ARGS__; } \
} while (0)

__device__ __forceinline__ void ld4(float* d, const float* p) {
  const float4 v = *(const float4*)p; d[0]=v.x; d[1]=v.y; d[2]=v.z; d[3]=v.w;
}

// C(64x64) OP= X(64xKD)@Y(KDx64).  OP: 0 assign, 1 add, 2 subtract. 256 threads, 4x4 tiles.
template<int KD, int LDX, int LDY, int LDC, int OP>
__device__ __forceinline__ void mmNN(float* C, const float* X, const float* Y) {
  const int t = threadIdx.x;
  const int ti = (t >> 4) << 2, tj = (t & 15) << 2;
  float c[4][4] = {};
  #pragma unroll
  for (int m = 0; m < KD; m += 4) {
    float xv[4][4], yv[4][4];
    #pragma unroll
    for (int r = 0; r < 4; ++r) ld4(xv[r], &X[(ti + r) * LDX + m]);
    #pragma unroll
    for (int k = 0; k < 4; ++k) ld4(yv[k], &Y[(m + k) * LDY + tj]);
    #pragma unroll
    for (int r = 0; r < 4; ++r)
      #pragma unroll
      for (int k = 0; k < 4; ++k)
        #pragma unroll
        for (int j = 0; j < 4; ++j) c[r][j] += xv[r][k] * yv[k][j];
  }
  #pragma unroll
  for (int r = 0; r < 4; ++r) {
    float* dst = &C[(ti + r) * LDC + tj];
    #pragma unroll
    for (int j = 0; j < 4; ++j) {
      if (OP == 0) dst[j] = c[r][j];
      else if (OP == 1) dst[j] += c[r][j];
      else dst[j] -= c[r][j];
    }
  }
}

// C(64x64) OP= X^T @ Y  (X stored KDx64 row-major; reads X[m][ti..ti+3] as float4)
template<int KD, int LDX, int LDY, int LDC, int OP>
__device__ __forceinline__ void mmTN(float* C, const float* X, const float* Y) {
  const int t = threadIdx.x;
  const int ti = (t >> 4) << 2, tj = (t & 15) << 2;
  float c[4][4] = {};
  #pragma unroll
  for (int m = 0; m < KD; m += 4) {
    float xq[4][4], yv[4][4];
    #pragma unroll
    for (int k = 0; k < 4; ++k) ld4(xq[k], &X[(m + k) * LDX + ti]);  // xq[k][r] = X^T[ti+r][m+k]
    #pragma unroll
    for (int k = 0; k < 4; ++k) ld4(yv[k], &Y[(m + k) * LDY + tj]);
    #pragma unroll
    for (int r = 0; r < 4; ++r)
      #pragma unroll
      for (int k = 0; k < 4; ++k)
        #pragma unroll
        for (int j = 0; j < 4; ++j) c[r][j] += xq[k][r] * yv[k][j];
  }
  #pragma unroll
  for (int r = 0; r < 4; ++r) {
    float* dst = &C[(ti + r) * LDC + tj];
    #pragma unroll
    for (int j = 0; j < 4; ++j) {
      if (OP == 0) dst[j] = c[r][j];
      else if (OP == 1) dst[j] += c[r][j];
      else dst[j] -= c[r][j];
    }
  }
}

// C(64x64) OP= X @ Yt^T  (Yt stored 64xKD row-major; Y[m][j] = Yt[j][m])
template<int KD, int LDX, int LDYT, int LDC, int OP>
__device__ __forceinline__ void mmNT(float* C, const float* X, const float* Yt) {
  const int t = threadIdx.x;
  const int ti = (t >> 4) << 2, tj = (t & 15) << 2;
  float c[4][4] = {};
  #pragma unroll
  for (int m = 0; m < KD; m += 4) {
    float xv[4][4], yq[4][4];
    #pragma unroll
    for (int r = 0; r < 4; ++r) ld4(xv[r], &X[(ti + r) * LDX + m]);
    #pragma unroll
    for (int cc = 0; cc < 4; ++cc) ld4(yq[cc], &Yt[(tj + cc) * LDYT + m]); // yq[cc][k] = Y[m+k][tj+cc]
    #pragma unroll
    for (int r = 0; r < 4; ++r)
      #pragma unroll
      for (int k = 0; k < 4; ++k)
        #pragma unroll
        for (int j = 0; j < 4; ++j) c[r][j] += xv[r][k] * yq[j][k];
  }
  #pragma unroll
  for (int r = 0; r < 4; ++r) {
    float* dst = &C[(ti + r) * LDC + tj];
    #pragma unroll
    for (int j = 0; j < 4; ++j) {
      if (OP == 0) dst[j] = c[r][j];
      else if (OP == 1) dst[j] += c[r][j];
      else dst[j] -= c[r][j];
    }
  }
}

// out(64) = M(64x64, ld ldm) @ v(64). 256 threads: 4 K-partials per row, LDS reduce.
__device__ __forceinline__ void mv64(float* out, const float* M, int ldm, const float* v, float* red) {
  const int t = threadIdx.x;
  const int r = t & 63, q = t >> 6, m0 = q << 4;
  float s = 0.f;
  #pragma unroll
  for (int m = 0; m < 16; ++m) s += M[r*ldm + m0 + m] * v[m0 + m];
  red[(q << 6) + r] = s;
  __syncthreads();
  if (t < 64) out[t] = (red[t] + red[64+t]) + (red[128+t] + red[192+t]);
  __syncthreads();
}

// out = (wa*Ma + wb*Mb) @ v, Ma/Mb global 64x64 (ld 64)
__device__ __forceinline__ void mv64_blend(float* out, const float* Ma, const float* Mb,
                                           float wa, float wb, const float* v, float* red) {
  const int t = threadIdx.x;
  const int r = t & 63, q = t >> 6, m0 = q << 4;
  float sa = 0.f, sb = 0.f;
  #pragma unroll
  for (int m = 0; m < 16; ++m) {
    const float vv = v[m0 + m];
    sa += Ma[r*64 + m0 + m] * vv;
    sb += Mb[r*64 + m0 + m] * vv;
  }
  red[(q << 6) + r] = wa*sa + wb*sb;
  __syncthreads();
  if (t < 64) out[t] = (red[t] + red[64+t]) + (red[128+t] + red[192+t]);
  __syncthreads();
}

__device__ __forceinline__ float dot64g(const float* __restrict__ a, const float* v) {
  float s = 0.f;
  #pragma unroll
  for (int m = 0; m < 64; m += 4) {
    const float4 av = *(const float4*)&a[m];
    s += av.x*v[m] + av.y*v[m+1] + av.z*v[m+2] + av.w*v[m+3];
  }
  return s;
}

// replicate jnp searchsorted-based linear interp on the uniform grid g[i] = DT*i
__device__ __forceinline__ void interpIW(float t, int imax, int& i, float& w) {
  int ii = (int)floorf(t * 50.0f);
  ii = ii < 0 ? 0 : (ii > imax ? imax : ii);
  const float gi  = DT * (float)ii;
  const float gi1 = DT * (float)(ii + 1);
  float ww = (t - gi) / (gi1 - gi);
  ww = fminf(fmaxf(ww, 0.0f), 1.0f);
  i = ii; w = ww;
}

// ================= prep kernels =================
__global__ void kPrepA(const float* __restrict__ Rg, const float* __restrict__ Bg, float* __restrict__ ws) {
  __shared__ float M[8][17];
  __shared__ int spiv;
  const int t = threadIdx.x;   // 64 threads
  if (t < 8) {
    #pragma unroll
    for (int c = 0; c < 8; ++c) { M[t][c] = Rg[t*8 + c]; M[t][8 + c] = (t == c) ? 1.0f : 0.0f; }
  }
  __syncthreads();
  for (int col = 0; col < 8; ++col) {
    if (t == 0) {
      int piv = col; float best = fabsf(M[col][col]);
      for (int r = col + 1; r < 8; ++r) { const float a = fabsf(M[r][col]); if (a > best) { best = a; piv = r; } }
      spiv = piv;
    }
    __syncthreads();
    const int piv = spiv;
    if (piv != col && t < 16) { const float tmp = M[col][t]; M[col][t] = M[piv][t]; M[piv][t] = tmp; }
    __syncthreads();
    if (t < 16) { const float pv = M[col][col]; M[col][t] = M[col][t] / pv; }
    __syncthreads();
    if (t < 8 && t != col) {
      const float f = M[t][col];
      #pragma unroll
      for (int c = 0; c < 16; ++c) M[t][c] -= f * M[col][c];
    }
    __syncthreads();
  }
  if (t < 64) ws[O_RI + t] = M[t >> 3][8 + (t & 7)];
  __syncthreads();
  for (int o = t; o < 512; o += 64) {
    const int i = o >> 3, l = o & 7;
    float s = 0.f;
    #pragma unroll
    for (int p = 0; p < 8; ++p) s += Bg[i*8 + p] * M[p][8 + l];
    ws[O_BRI + o] = s;                     // (B@Ri)[i][l]
    const int p2 = o >> 6, j2 = o & 63;
    float s2 = 0.f;
    #pragma unroll
    for (int l2 = 0; l2 < 8; ++l2) s2 += M[p2][8 + l2] * Bg[j2*8 + l2];
    ws[O_RIBT + o] = s2;                   // (Ri@B^T)[p2][j2]
    ws[O_BT + o] = Bg[j2*8 + p2];          // B^T[p2][j2]
  }
}

__global__ void kPrepB(const float* __restrict__ Hg, float* __restrict__ ws, float* __restrict__ out) {
  const int total = 32768 + 32768 + 8000;
  for (int idx = blockIdx.x * 256 + threadIdx.x; idx < total; idx += gridDim.x * 256) {
    if (idx < 32768) {
      const int j = idx >> 9, l = (idx >> 6) & 7, n = idx & 63;
      ws[O_H1 + idx] = Hg[j*512 + n*8 + l];
    } else if (idx < 65536) {
      const int k2 = idx - 32768;
      const int j = k2 >> 9, s = (k2 >> 6) & 7, m = k2 & 63;
      ws[O_H2 + k2] = Hg[m*512 + j*8 + s];
    } else {
      out[O_U0o + (idx - 65536)] = 0.0f;   // u_res[0] = 0
    }
  }
}

// ================= LQR Riccati: Ps backward =================
__global__ void __launch_bounds__(256) kP(const float* __restrict__ Fg, const float* __restrict__ Qg,
                                          const float* __restrict__ Ag,
                                          const float* __restrict__ ws, float* __restrict__ Ps) {
  __shared__ float y0[64*LDM], acc[64*LDM], ytm[64*LDM], kb[64*LDM];
  __shared__ float As[64*LDM], ATs[64*LDM], Qs[64*LDM];
  __shared__ float BTs[512], Ris[64], yB[512], M2s[512], T8[8*LDM], red[256];
  const int t = threadIdx.x;
  { const int r = t >> 2, c0 = (t & 3) << 4;
    #pragma unroll
    for (int e = 0; e < 16; ++e) { const int c = c0 + e;
      y0[r*LDM + c]  = Fg[r*64 + c];
      As[r*LDM + c]  = Ag[r*64 + c];
      ATs[c*LDM + r] = Ag[r*64 + c];
      Qs[r*LDM + c]  = Qg[r*64 + c];
    } }
  for (int o = t; o < 512; o += 256) BTs[o] = ws[O_BT + o];
  if (t < 64) Ris[t] = ws[O_RI + t];
  __syncthreads();
  { const int r = t >> 2, c0 = (t & 3) << 4;
    #pragma unroll
    for (int e = 0; e < 16; ++e) Ps[(size_t)NTS*4096 + r*64 + c0 + e] = y0[r*LDM + c0 + e]; }

  const float dt = -DT;
  const float c16 = dt / 6.0f, c13 = 2.0f * c16, c12 = 0.5f * dt;

  auto field = [&](const float* src) {
    for (int o = t; o < 512; o += 256) {              // yB = src@B
      const int i = o >> 3, l = o & 7;
      const float* sr = &src[i*LDM];
      const float* br = &BTs[l*64];
      float s = 0.f;
      #pragma unroll
      for (int m = 0; m < 64; ++m) s += sr[m] * br[m];
      yB[o] = s;
    }
    __syncthreads();
    for (int o = t; o < 512; o += 256) {              // M2 = yB@Ri
      const int i = o >> 3, l = o & 7;
      float s = 0.f;
      #pragma unroll
      for (int p = 0; p < 8; ++p) s += yB[i*8 + p] * Ris[p*8 + l];
      M2s[o] = s;
    }
    for (int o = t; o < 512; o += 256) {              // T8 = B^T@src
      const int p = o >> 6, jj = o & 63;
      const float* br = &BTs[p*64];
      float s = 0.f;
      #pragma unroll
      for (int m = 0; m < 64; ++m) s += br[m] * src[m*LDM + jj];
      T8[p*LDM + jj] = s;
    }
    __syncthreads();
    mmNN<8,  8,   LDM, LDM, 0>(kb, M2s, T8);          // kb  = yBRi @ B^Ty
    mmNN<64, LDM, LDM, LDM, 2>(kb, src, As);          // kb -= y@A
    mmNN<64, LDM, LDM, LDM, 2>(kb, ATs, src);         // kb -= A^T@y
    __syncthreads();
  };

  for (int j = 0; j < NTS; ++j) {
    for (int st = 0; st < 4; ++st) {
      const float* src = (st == 0) ? y0 : ytm;
      field(src);
      EW_FOR(I, J, IJ, {
        const float kv = kb[IJ] - Qs[IJ];             // field value
        if (st == 0)      { acc[IJ] = y0[IJ] + c16*kv; ytm[IJ] = y0[IJ] + c12*kv; }
        else if (st == 1) { acc[IJ] += c13*kv;         ytm[IJ] = y0[IJ] + c12*kv; }
        else if (st == 2) { acc[IJ] += c13*kv;         ytm[IJ] = y0[IJ] + dt*kv;  }
        else              { y0[IJ] = acc[IJ] + c16*kv; }
      });
      __syncthreads();
    }
    { const int r = t >> 2, c0 = (t & 3) << 4;
      float4* dst = (float4*)&Ps[(size_t)(NTS-1-j)*4096 + r*64 + c0];
      #pragma unroll
      for (int e = 0; e < 4; ++e) {
        const float* s4 = &y0[r*LDM + c0 + 4*e];
        dst[e] = make_float4(s4[0], s4[1], s4[2], s4[3]);
      } }
    __syncthreads();
  }
}

// ================= iteration 0: x' = A x =================
__global__ void __launch_bounds__(256) kX0(const float* __restrict__ Ag, const float* __restrict__ x0g,
                                           float* __restrict__ out) {
  __shared__ float As[64*LDM], xv[64], xt[64], ks[4][64], red[256];
  const int t = threadIdx.x;
  { const int r = t >> 2, c0 = (t & 3) << 4;
    #pragma unroll
    for (int e = 0; e < 16; ++e) As[r*LDM + c0 + e] = Ag[r*64 + c0 + e]; }
  if (t < 64) xv[t] = x0g[t];
  __syncthreads();
  for (int j = 0; j < NTS; ++j) {
    if (t < 64) out[O_X0o + j*64 + t] = xv[t];
    __syncthreads();
    if (j == NTS - 1) break;
    for (int st = 0; st < 4; ++st) {
      const float* src = (st == 0) ? xv : xt;
      mv64(ks[st], As, LDM, src, red);
      if (t < 64 && st < 3) xt[t] = xv[t] + (st == 2 ? DT : 0.01f) * ks[st][t];
      __syncthreads();
    }
    if (t < 64) xv[t] += (DT/6.0f) * (ks[0][t] + 2.0f*ks[1][t] + 2.0f*ks[2][t] + ks[3][t]);
    __syncthreads();
  }
}

// ================= iteration 1: LQR sweep + u1 =================
__global__ void __launch_bounds__(256) kXgrid(const float* __restrict__ Ag, const float* __restrict__ Bg,
                                              const float* __restrict__ x0g,
                                              float* __restrict__ ws, float* __restrict__ out) {
  __shared__ float As[64*LDM], Bs[512], RiBTs[512];
  __shared__ float xv[64], xt[64], ks[4][64], pv[64], g8[8], red[256];
  const int t = threadIdx.x;
  const float* Ps = ws + O_PS;
  { const int r = t >> 2, c0 = (t & 3) << 4;
    #pragma unroll
    for (int e = 0; e < 16; ++e) As[r*LDM + c0 + e] = Ag[r*64 + c0 + e]; }
  for (int o = t; o < 512; o += 256) { Bs[o] = Bg[o]; RiBTs[o] = ws[O_RIBT + o]; }
  if (t < 64) xv[t] = x0g[t];
  __syncthreads();

  auto field = [&](float tau, const float* src, float* kout) {
    int i; float w; interpIW(tau, NTS - 1, i, w);
    mv64_blend(pv, Ps + (size_t)i*4096, Ps + (size_t)(i+1)*4096, 1.0f - w, w, src, red);
    if (t < 8) {
      float s = 0.f;
      #pragma unroll
      for (int m = 0; m < 64; ++m) s += RiBTs[t*64 + m] * pv[m];
      g8[t] = s;
    }
    mv64(kout, As, LDM, src, red);                    // A@y (g8 visible after internal barrier)
    if (t < 64) {
      float s = 0.f;
      #pragma unroll
      for (int p = 0; p < 8; ++p) s += Bs[t*8 + p] * g8[p];
      kout[t] -= s;                                   // - B@(RiB^T P y)
    }
    __syncthreads();
  };

  for (int j = 0; j < NTS; ++j) {
    if (t < 64) { out[O_X1o + j*64 + t] = xv[t]; ws[O_XG + j*64 + t] = xv[t]; }
    mv64(pv, Ps + (size_t)j*4096, 64, xv, red);       // exact-grid Ps[j]@x for u1
    if (t < 8) {
      float s = 0.f;
      #pragma unroll
      for (int m = 0; m < 64; ++m) s += RiBTs[t*64 + m] * pv[m];
      out[O_U1o + j*8 + t] = -s;
    }
    __syncthreads();
    if (j == NTS - 1) break;
    const float tj = DT * (float)j;
    for (int st = 0; st < 4; ++st) {
      const float tau = tj + ((st == 0) ? 0.0f : (st == 3) ? DT : 0.01f);
      const float* src = (st == 0) ? xv : xt;
      field(tau, src, ks[st]);
      if (t < 64 && st < 3) xt[t] = xv[t] + (st == 2 ? DT : 0.01f) * ks[st][t];
      __syncthreads();
    }
    if (t < 64) xv[t] += (DT/6.0f) * (ks[0][t] + 2.0f*ks[1][t] + 2.0f*ks[2][t] + ks[3][t]);
    __syncthreads();
  }
}

// ================= x_k1: forward sweep with A_k =================
__global__ void __launch_bounds__(256) kXk1(const float* __restrict__ Ag, const float* __restrict__ Bg,
                                            const float* __restrict__ Hg, const float* __restrict__ x0g,
                                            float* __restrict__ ws) {
  __shared__ float Atil[64*LDM];
  __shared__ float Bs[512], BTs[512], RiBTs[512], BRis[512], Ris[64];
  __shared__ float Hx[512], Bt[512], BtRi[512], G[512];
  __shared__ float xv[64], xt[64], xk[64], pk[64], pv[64], sv[64];
  __shared__ float ks[4][64], e1[8], e2[8], e3[8], e8v[8], w8[8], red[256];
  __shared__ int ci; __shared__ float cw;
  const int t = threadIdx.x;
  const float* Ps = ws + O_PS;
  const float* xg = ws + O_XG;
  for (int o = t; o < 512; o += 256) {
    Bs[o] = Bg[o]; BTs[o] = ws[O_BT + o]; RiBTs[o] = ws[O_RIBT + o]; BRis[o] = ws[O_BRI + o];
  }
  if (t < 64) { Ris[t] = ws[O_RI + t]; xv[t] = x0g[t]; }
  __syncthreads();

  auto build = [&](float tau) {
    int i, ix; float w, wx;
    interpIW(tau, NTS - 1, i, w);
    interpIW(tau, NTS - 2, ix, wx);
    if (t == 0) { ci = i; cw = w; }
    if (t < 64) xk[t] = (1.0f - wx) * xg[ix*64 + t] + wx * xg[(ix+1)*64 + t];
    __syncthreads();
    mv64_blend(pk, Ps + (size_t)i*4096, Ps + (size_t)(i+1)*4096, 1.0f - w, w, xk, red);
    if (t < 8) {
      float s = 0.f;
      #pragma unroll
      for (int m = 0; m < 64; ++m) s += BTs[t*64 + m] * pk[m];
      e8v[t] = s;
    }
    __syncthreads();
    if (t < 8) {
      float s = 0.f;
      #pragma unroll
      for (int l = 0; l < 8; ++l) s += Ris[t*8 + l] * e8v[l];
      w8[t] = s;
    }
    for (int o = t; o < 512; o += 256) {
      const float hx = dot64g(&ws[O_H1 + o*64], xk);
      Hx[o] = hx; Bt[o] = Bs[o] + hx;
      G[o]  = dot64g(&ws[O_H2 + o*64], pk);
    }
    __syncthreads();
    for (int o = t; o < 512; o += 256) {
      const int i2 = o >> 3, l = o & 7;
      float s = 0.f;
      #pragma unroll
      for (int p = 0; p < 8; ++p) s += Bt[i2*8 + p] * Ris[p*8 + l];
      BtRi[o] = s;
    }
    EW_FOR(I, J, IJ, {                                 // T1 = H . w8
      const float4 h0 = *(const float4*)&Hg[I*512 + J*8];
      const float4 h1 = *(const float4*)&Hg[I*512 + J*8 + 4];
      Atil[IJ] = h0.x*w8[0]+h0.y*w8[1]+h0.z*w8[2]+h0.w*w8[3]
               + h1.x*w8[4]+h1.y*w8[5]+h1.z*w8[6]+h1.w*w8[7];
    });
    __syncthreads();
    mmNT<8, 8, 8, LDM, 1>(Atil, BRis, G);              // += BRi@G^T
    __syncthreads();
    EW_FOR(I, J, IJ, { Atil[IJ] = Ag[I*64 + J] - 0.5f*Atil[IJ]; });
    __syncthreads();
  };

  auto fieldK = [&](const float* src, float* kout) {
    mv64_blend(pv, Ps + (size_t)ci*4096, Ps + (size_t)(ci+1)*4096, 1.0f - cw, cw, src, red);
    if (t < 8) {                                       // e1 = Bt^T pv
      float s = 0.f;
      #pragma unroll
      for (int m = 0; m < 64; ++m) s += Bt[m*8 + t] * pv[m];
      e1[t] = s;
    } else if (t < 16) {                               // e2 = RiB^T pv
      const int l = t - 8; float s = 0.f;
      #pragma unroll
      for (int m = 0; m < 64; ++m) s += RiBTs[l*64 + m] * pv[m];
      e2[l] = s;
    } else if (t < 24) {                               // e3 = Hx^T pv
      const int l = t - 16; float s = 0.f;
      #pragma unroll
      for (int m = 0; m < 64; ++m) s += Hx[m*8 + l] * pv[m];
      e3[l] = s;
    }
    __syncthreads();
    if (t < 64) {                                      // sv = S @ (P y)
      float s1 = 0.f, s2 = 0.f, s3 = 0.f;
      #pragma unroll
      for (int p = 0; p < 8; ++p) {
        s1 += BtRi[t*8 + p] * e1[p];
        s2 += Hx[t*8 + p]   * e2[p];
        s3 += BRis[t*8 + p] * e3[p];
      }
      sv[t] = s1 - 0.5f*(s2 + s3);
    }
    mv64(kout, Atil, LDM, src, red);
    if (t < 64) kout[t] -= sv[t];
    __syncthreads();
  };

  for (int j = 0; j < NTS; ++j) {
    if (t < 64) ws[O_XK1 + j*64 + t] = xv[t];
    __syncthreads();
    if (j == NTS - 1) break;
    const float tj = DT * (float)j;
    for (int st = 0; st < 4; ++st) {
      if (st != 2) build(tj + ((st == 0) ? 0.0f : (st == 3) ? DT : 0.01f));
      const float* src = (st == 0) ? xv : xt;
      fieldK(src, ks[st]);
      if (t < 64 && st < 3) xt[t] = xv[t] + (st == 2 ? DT : 0.01f) * ks[st][t];
      __syncthreads();
    }
    if (t < 64) xv[t] += (DT/6.0f) * (ks[0][t] + 2.0f*ks[1][t] + 2.0f*ks[2][t] + ks[3][t]);
    __syncthreads();
  }
}

// ================= P_k1: backward matrix Riccati with A_k, Q_k =================
__global__ void __launch_bounds__(256) kPk1(const float* __restrict__ Fg, const float* __restrict__ Ag,
                                            const float* __restrict__ Bg, const float* __restrict__ Hg,
                                            float* __restrict__ ws) {
  __shared__ float y0[64*LDM], acc[64*LDM], ytm[64*LDM], kb[64*LDM];
  __shared__ float Pc[64*LDM], Ss[64*LDM], SP[64*LDM], Akt[64*LDM];
  __shared__ float Bs[512], BTs[512], RiBTs[512], BRis[512], Ris[64];
  __shared__ float Hx[512], Bt[512], BtRi[512], G[512], GRi[512];
  __shared__ float xk[64], pk[64], e8v[8], w8[8], red[256];
  const int t = threadIdx.x;
  const float* Ps = ws + O_PS;
  const float* xg = ws + O_XG;
  float* Pk1g = ws + O_PK1;
  { const int r = t >> 2, c0 = (t & 3) << 4;
    #pragma unroll
    for (int e = 0; e < 16; ++e) y0[r*LDM + c0 + e] = Fg[r*64 + c0 + e]; }
  for (int o = t; o < 512; o += 256) {
    Bs[o] = Bg[o]; BTs[o] = ws[O_BT + o]; RiBTs[o] = ws[O_RIBT + o]; BRis[o] = ws[O_BRI + o];
  }
  if (t < 64) Ris[t] = ws[O_RI + t];
  __syncthreads();

  const float dt = -DT;
  const float c16 = dt / 6.0f, c13 = 2.0f * c16, c12 = 0.5f * dt;

  auto build = [&](float tau) {
    int i, ix; float w, wx;
    interpIW(tau, NTS - 1, i, w);
    interpIW(tau, NTS - 2, ix, wx);
    if (t < 64) xk[t] = (1.0f - wx) * xg[ix*64 + t] + wx * xg[(ix+1)*64 + t];
    { const int r = t >> 2, c0 = (t & 3) << 4;                 // Pc = blend of Ps[i], Ps[i+1]
      const float4* pa = (const float4*)&Ps[(size_t)i*4096 + r*64 + c0];
      const float4* pb = (const float4*)&Ps[(size_t)(i+1)*4096 + r*64 + c0];
      const float wa = 1.0f - w;
      #pragma unroll
      for (int e = 0; e < 4; ++e) {
        const float4 a = pa[e], b = pb[e];
        float* d = &Pc[r*LDM + c0 + 4*e];
        d[0] = wa*a.x + w*b.x; d[1] = wa*a.y + w*b.y; d[2] = wa*a.z + w*b.z; d[3] = wa*a.w + w*b.w;
      } }
    __syncthreads();
    mv64(pk, Pc, LDM, xk, red);
    if (t < 8) {
      float s = 0.f;
      #pragma unroll
      for (int m = 0; m < 64; ++m) s += BTs[t*64 + m] * pk[m];
      e8v[t] = s;
    }
    __syncthreads();
    if (t < 8) {
      float s = 0.f;
      #pragma unroll
      for (int l = 0; l < 8; ++l) s += Ris[t*8 + l] * e8v[l];
      w8[t] = s;
    }
    for (int o = t; o < 512; o += 256) {
      const float hx = dot64g(&ws[O_H1 + o*64], xk);
      Hx[o] = hx; Bt[o] = Bs[o] + hx;
      G[o]  = dot64g(&ws[O_H2 + o*64], pk);
    }
    __syncthreads();
    for (int o = t; o < 512; o += 256) {
      const int i2 = o >> 3, l = o & 7;
      float s1 = 0.f, s2 = 0.f;
      #pragma unroll
      for (int p = 0; p < 8; ++p) { s1 += Bt[i2*8 + p] * Ris[p*8 + l]; s2 += G[i2*8 + p] * Ris[p*8 + l]; }
      BtRi[o] = s1; GRi[o] = s2;
    }
    __syncthreads();
    mmNN<8, 8, 64, LDM, 0>(kb, Hx, RiBTs);             // term3 = Hx @ RiB^T
    mmNT<8, 8, 8,  LDM, 0>(Ss, BtRi, Bt);              // Bt Ri Bt^T
    __syncthreads();
    EW_FOR(I, J, IJ, { Ss[IJ] = Ss[IJ] - 0.5f*(kb[IJ] + kb[J*LDM + I]); });  // S
    __syncthreads();
    mmNN<64, LDM, LDM, LDM, 0>(SP, Ss, Pc);            // SP = S@P
    __syncthreads();
    mmNN<64, LDM, LDM, LDM, 0>(kb, Pc, SP);            // kb = P@S@P
    mmNT<8, 8, 8, LDM, 0>(Ss, GRi, G);                 // Ss = M = G Ri G^T
    __syncthreads();
    EW_FOR(I, J, IJ, {
      Pc[IJ] = Ss[IJ] + Ss[J*LDM + I] - kb[IJ];        // Q_k (reuses Pc buffer)
      const float4 h0 = *(const float4*)&Hg[I*512 + J*8];
      const float4 h1 = *(const float4*)&Hg[I*512 + J*8 + 4];
      Akt[IJ] = h0.x*w8[0]+h0.y*w8[1]+h0.z*w8[2]+h0.w*w8[3]
              + h1.x*w8[4]+h1.y*w8[5]+h1.z*w8[6]+h1.w*w8[7];   // T1
    });
    __syncthreads();
    mmNT<8, 8, 8, LDM, 1>(Akt, BRis, G);               // += BRi@G^T
    __syncthreads();
    EW_FOR(I, J, IJ, { Akt[IJ] = Ag[I*64 + J] - 0.5f*Akt[IJ] - SP[IJ]; });   // A_k
    __syncthreads();
  };

  auto evalf = [&](const float* src) {
    mmNN<64, LDM, LDM, LDM, 0>(kb, src, Akt);
    mmTN<64, LDM, LDM, LDM, 1>(kb, Akt, src);
    __syncthreads();
  };

  for (int j = 0; j < NTS; ++j) {
    const float tj = 20.0f - DT * (float)j;
    for (int st = 0; st < 4; ++st) {
      if (st != 2) build(tj - ((st == 0) ? 0.0f : (st == 3) ? DT : 0.01f));
      const float* src = (st == 0) ? y0 : ytm;
      evalf(src);
      EW_FOR(I, J, IJ, {
        const float kv = -(kb[IJ] + Pc[IJ]);           // -yA_k - A_k^T y - Q_k
        if (st == 0)      { acc[IJ] = y0[IJ] + c16*kv; ytm[IJ] = y0[IJ] + c12*kv; }
        else if (st == 1) { acc[IJ] += c13*kv;         ytm[IJ] = y0[IJ] + c12*kv; }
        else if (st == 2) { acc[IJ] += c13*kv;         ytm[IJ] = y0[IJ] + dt*kv;  }
        else              { y0[IJ] = acc[IJ] + c16*kv; }
      });
      __syncthreads();
    }
    { const int r = t >> 2, c0 = (t & 3) << 4;
      float4* dst = (float4*)&Pk1g[(size_t)(NTS-1-j)*4096 + r*64 + c0];
      #pragma unroll
      for (int e = 0; e < 4; ++e) {
        const float* s4 = &y0[r*LDM + c0 + 4*e];
        dst[e] = make_float4(s4[0], s4[1], s4[2], s4[3]);
      } }
    __syncthreads();
  }
}

// ================= u_grid (parallel over time) =================
__global__ void __launch_bounds__(256) kUgrid(const float* __restrict__ ws, float* __restrict__ out) {
  const int j = blockIdx.x, t = threadIdx.x;
  __shared__ float xvj[64], x1[64], vv[64], hxv[512], w8s[8], Ris[64], red[256];
  if (t < 64) { xvj[t] = ws[O_XG + j*64 + t]; x1[t] = ws[O_XK1 + j*64 + t]; Ris[t] = ws[O_RI + t]; }
  __syncthreads();
  mv64(vv, ws + O_PK1 + (size_t)j*4096, 64, x1, red);  // v = P_k1[j] @ x_k1[j]
  for (int o = t; o < 512; o += 256) {
    const int j2 = o >> 3;
    hxv[o] = vv[j2] * dot64g(&ws[O_H1 + o*64], xvj);   // Hx[j2][l] * v[j2]
  }
  __syncthreads();
  if (t < 8) {
    float s = 0.f;
    #pragma unroll
    for (int j2 = 0; j2 < 64; ++j2) s += hxv[j2*8 + t];
    w8s[t] = s;
  }
  __syncthreads();
  if (t < 8) {
    float s = 0.f;
    #pragma unroll
    for (int l = 0; l < 8; ++l) s += Ris[t*8 + l] * w8s[l];
    out[O_U2o + j*8 + t] = -s;                         // u = -Ri @ w
  }
}

// ================= x_eval: forward sweep with A_k_tilde + B_k_tilde u =================
__global__ void __launch_bounds__(256) kXeval(const float* __restrict__ Ag, const float* __restrict__ Bg,
                                              const float* __restrict__ Hg, const float* __restrict__ x0g,
                                              float* __restrict__ ws, float* __restrict__ out) {
  __shared__ float Atil[64*LDM];
  __shared__ float Bs[512], BTs[512], BRis[512], Ris[64];
  __shared__ float Hx[512], Bt[512], G[512];
  __shared__ float xv[64], xt[64], xk[64], pk[64], bu[64];
  __shared__ float ks[4][64], e8v[8], w8[8], uu8[8], red[256];
  const int t = threadIdx.x;
  const float* Ps = ws + O_PS;
  const float* xg = ws + O_XG;
  const float* Ug = out + O_U2o;
  for (int o = t; o < 512; o += 256) { Bs[o] = Bg[o]; BTs[o] = ws[O_BT + o]; BRis[o] = ws[O_BRI + o]; }
  if (t < 64) { Ris[t] = ws[O_RI + t]; xv[t] = x0g[t]; }
  __syncthreads();

  auto build = [&](float tau) {
    int i, ix; float w, wx;
    interpIW(tau, NTS - 1, i, w);
    interpIW(tau, NTS - 2, ix, wx);
    if (t < 64) xk[t] = (1.0f - wx) * xg[ix*64 + t] + wx * xg[(ix+1)*64 + t];
    __syncthreads();
    mv64_blend(pk, Ps + (size_t)i*4096, Ps + (size_t)(i+1)*4096, 1.0f - w, w, xk, red);
    if (t < 8) {
      float s = 0.f;
      #pragma unroll
      for (int m = 0; m < 64; ++m) s += BTs[t*64 + m] * pk[m];
      e8v[t] = s;
    }
    __syncthreads();
    if (t < 8) {
      float s = 0.f;
      #pragma unroll
      for (int l = 0; l < 8; ++l) s += Ris[t*8 + l] * e8v[l];
      w8[t] = s;
    }
    for (int o = t; o < 512; o += 256) {
      const float hx = dot64g(&ws[O_H1 + o*64], xk);
      Hx[o] = hx; Bt[o] = Bs[o] + hx;
      G[o]  = dot64g(&ws[O_H2 + o*64], pk);
    }
    __syncthreads();
    EW_FOR(I, J, IJ, {
      const float4 h0 = *(const float4*)&Hg[I*512 + J*8];
      const float4 h1 = *(const float4*)&Hg[I*512 + J*8 + 4];
      Atil[IJ] = h0.x*w8[0]+h0.y*w8[1]+h0.z*w8[2]+h0.w*w8[3]
               + h1.x*w8[4]+h1.y*w8[5]+h1.z*w8[6]+h1.w*w8[7];
    });
    __syncthreads();
    mmNT<8, 8, 8, LDM, 1>(Atil, BRis, G);
    __syncthreads();
    EW_FOR(I, J, IJ, { Atil[IJ] = Ag[I*64 + J] - 0.5f*Atil[IJ]; });
    if (t < 8) uu8[t] = (1.0f - wx) * Ug[ix*8 + t] + wx * Ug[(ix+1)*8 + t];  // u interp (ts grid)
    __syncthreads();
    if (t < 64) {
      float s = 0.f;
      #pragma unroll
      for (int l = 0; l < 8; ++l) s += Bt[t*8 + l] * uu8[l];                 // B_k_tilde @ u
      bu[t] = s;
    }
    __syncthreads();
  };

  auto fieldE = [&](const float* src, float* kout) {
    mv64(kout, Atil, LDM, src, red);
    if (t < 64) kout[t] += bu[t];
    __syncthreads();
  };

  for (int j = 0; j < NTS; ++j) {
    if (t < 64) out[O_X2o + j*64 + t] = xv[t];
    __syncthreads();
    if (j == NTS - 1) break;
    const float tj = DT * (float)j;
    for (int st = 0; st < 4; ++st) {
      if (st != 2) build(tj + ((st == 0) ? 0.0f : (st == 3) ? DT : 0.01f));
      const float* src = (st == 0) ? xv : xt;
      fieldE(src, ks[st]);
      if (t < 64 && st < 3) xt[t] = xv[t] + (st == 2 ? DT : 0.01f) * ks[st][t];
      __syncthreads();
    }
    if (t < 64) xv[t] += (DT/6.0f) * (ks[0][t] + 2.0f*ks[1][t] + 2.0f*ks[2][t] + ks[3][t]);
    __syncthreads();
  }
}

// ================= launch =================
extern "C" void kernel_launch(void* const* d_in, const int* in_sizes, int n_in,
                              void* d_out, int out_size, void* d_ws, size_t ws_size,
                              hipStream_t stream) {
  const float* F  = (const float*)d_in[0];
  const float* Q  = (const float*)d_in[1];
  const float* R  = (const float*)d_in[2];
  const float* A  = (const float*)d_in[3];
  const float* B  = (const float*)d_in[4];
  const float* H  = (const float*)d_in[5];
  const float* x0 = (const float*)d_in[6];
  float* out = (float*)d_out;
  float* ws  = (float*)d_ws;
  (void)in_sizes; (void)n_in; (void)out_size; (void)ws_size;  // needs ws_size >= ~33.6 MB

  kPrepA<<<1, 64, 0, stream>>>(R, B, ws);
  kPrepB<<<96, 256, 0, stream>>>(H, ws, out);
  kP<<<1, 256, 0, stream>>>(F, Q, A, ws, ws + O_PS);
  kX0<<<1, 256, 0, stream>>>(A, x0, out);
  kXgrid<<<1, 256, 0, stream>>>(A, B, x0, ws, out);
  kXk1<<<1, 256, 0, stream>>>(A, B, H, x0, ws);
  kPk1<<<1, 256, 0, stream>>>(F, A, B, H, ws);
  kUgrid<<<NTS, 256, 0, stream>>>(ws, out);
  kXeval<<<1, 256, 0, stream>>>(A, B, H, x0, ws, out);
}

// Round 4
// 184289.221 us; speedup vs baseline: 1.2451x; 1.2451x over previous
//
#include <hip/hip_runtime.h>
#include <cmath>

// Quantum bilinear controller solver (N=64, K=8, NT=1000, N_its=2), fp32.
// Sequential sweeps: ONE workgroup of 1024 threads (16 waves) with state in LDS.
// All global matrix reads coalesced (P matrices read column-wise via symmetry,
// H read via natural layout (G) and a transposed copy H1T (Hx)).

#define NTS 1000
#define DT  0.02f
#define LDM 68          // padded leading dim for 64-col LDS matrices (rows 16B aligned)

// ---------------- workspace layout (floats) ----------------
constexpr int O_PS   = 0;                       // (NTS+1) x 64 x 64 (symmetric each)
constexpr int O_PK1  = O_PS  + (NTS+1)*4096;    // NTS x 64 x 64 (symmetric each)
constexpr int O_XG   = O_PK1 + NTS*4096;        // NTS x 64
constexpr int O_XK1  = O_XG  + NTS*64;          // NTS x 64
constexpr int O_H1T  = O_XK1 + NTS*64;          // H1T[n][o] = H[j][n][l], o=j*8+l  (64x512)
constexpr int O_RI   = O_H1T + 64*512;          // Ri (8x8)
constexpr int O_BRI  = O_RI  + 64;              // B@Ri    (64x8)
constexpr int O_RIBT = O_BRI + 512;             // Ri@B^T  (8x64)
constexpr int O_BT   = O_RIBT+ 512;             // B^T     (8x64)

// ---------------- output layout (floats) ----------------
constexpr int O_X0o = 0;        // x_res[0]  (1000x64)
constexpr int O_X1o = 64000;    // x_res[1]
constexpr int O_X2o = 128000;   // x_res[2]
constexpr int O_U0o = 192000;   // u_res[0] (zeros)
constexpr int O_U1o = 200000;   // u_res[1]
constexpr int O_U2o = 208000;   // u_res[2]

// elementwise pass over 64x64 padded LDS matrix, 1024 threads, 4 elems each
#define EW4(I, J, IJ, ...) do { \
  const int _r = (int)threadIdx.x >> 4; const int _c0 = ((int)threadIdx.x & 15) << 2; \
  _Pragma("unroll") \
  for (int _e = 0; _e < 4; ++_e) { const int I = _r; const int J = _c0 + _e; const int IJ = (I)*LDM + (J); __VA_ARGS__; } \
} while (0)

__device__ __forceinline__ float wred64(float v) {
  v += __shfl_down(v, 32, 64);
  v += __shfl_down(v, 16, 64);
  v += __shfl_down(v, 8, 64);
  v += __shfl_down(v, 4, 64);
  v += __shfl_down(v, 2, 64);
  v += __shfl_down(v, 1, 64);
  return v;
}

// C(64x64) OP= X(64xKD)@Y(KDx64). 1024 threads: 1 row x 4 cols per thread.
template<int KD, int LDX, int LDY, int LDC, int OP>
__device__ __forceinline__ void mmNN(float* C, const float* X, const float* Y) {
  const int t = threadIdx.x;
  const int row = t >> 4, tj = (t & 15) << 2;
  float c0 = 0.f, c1 = 0.f, c2 = 0.f, c3 = 0.f;
  #pragma unroll
  for (int m = 0; m < KD; m += 4) {
    const float4 x4 = *(const float4*)&X[row*LDX + m];
    const float4 ya = *(const float4*)&Y[(m+0)*LDY + tj];
    const float4 yb = *(const float4*)&Y[(m+1)*LDY + tj];
    const float4 yc = *(const float4*)&Y[(m+2)*LDY + tj];
    const float4 yd = *(const float4*)&Y[(m+3)*LDY + tj];
    c0 += x4.x*ya.x + x4.y*yb.x + x4.z*yc.x + x4.w*yd.x;
    c1 += x4.x*ya.y + x4.y*yb.y + x4.z*yc.y + x4.w*yd.y;
    c2 += x4.x*ya.z + x4.y*yb.z + x4.z*yc.z + x4.w*yd.z;
    c3 += x4.x*ya.w + x4.y*yb.w + x4.z*yc.w + x4.w*yd.w;
  }
  float* dst = &C[row*LDC + tj];
  if (OP == 0)      { dst[0] = c0; dst[1] = c1; dst[2] = c2; dst[3] = c3; }
  else if (OP == 1) { dst[0] += c0; dst[1] += c1; dst[2] += c2; dst[3] += c3; }
  else              { dst[0] -= c0; dst[1] -= c1; dst[2] -= c2; dst[3] -= c3; }
}

// C(64x64) OP= X(64xKD) @ Yt^T (Yt stored 64xKD row-major). 1024 threads.
template<int KD, int LDX, int LDYT, int LDC, int OP>
__device__ __forceinline__ void mmNT(float* C, const float* X, const float* Yt) {
  const int t = threadIdx.x;
  const int row = t >> 4, tj = (t & 15) << 2;
  float c[4] = {0.f, 0.f, 0.f, 0.f};
  #pragma unroll
  for (int m = 0; m < KD; m += 4) {
    const float4 x4 = *(const float4*)&X[row*LDX + m];
    #pragma unroll
    for (int j = 0; j < 4; ++j) {
      const float4 y4 = *(const float4*)&Yt[(tj+j)*LDYT + m];
      c[j] += x4.x*y4.x + x4.y*y4.y + x4.z*y4.z + x4.w*y4.w;
    }
  }
  float* dst = &C[row*LDC + tj];
  #pragma unroll
  for (int j = 0; j < 4; ++j) {
    if (OP == 0) dst[j] = c[j];
    else if (OP == 1) dst[j] += c[j];
    else dst[j] -= c[j];
  }
}

// out(64) = M(LDS row-major, ld LDM) @ v. 1024 threads, 4 MACs each.
__device__ __forceinline__ void mvL(float* out, const float* M, const float* v, float* red) {
  const int t = threadIdx.x, r = t & 63, m0 = (t >> 6) << 2;
  float s = M[r*LDM+m0]*v[m0] + M[r*LDM+m0+1]*v[m0+1]
          + M[r*LDM+m0+2]*v[m0+2] + M[r*LDM+m0+3]*v[m0+3];
  red[t] = s;
  __syncthreads();
  if (t < 64) {
    float a = 0.f;
    #pragma unroll
    for (int q = 0; q < 16; ++q) a += red[q*64 + t];
    out[t] = a;
  }
  __syncthreads();
}

// out(64) = M @ v for SYMMETRIC LDS matrix M (column reads: conflict-free)
__device__ __forceinline__ void mvLsym(float* out, const float* M, const float* v, float* red) {
  const int t = threadIdx.x, r = t & 63, m0 = (t >> 6) << 2;
  float s = 0.f;
  #pragma unroll
  for (int k = 0; k < 4; ++k) s += M[(m0+k)*LDM + r] * v[m0+k];
  red[t] = s;
  __syncthreads();
  if (t < 64) {
    float a = 0.f;
    #pragma unroll
    for (int q = 0; q < 16; ++q) a += red[q*64 + t];
    out[t] = a;
  }
  __syncthreads();
}

// out(64) = Mg @ v for SYMMETRIC global matrix (ld 64): coalesced column reads
__device__ __forceinline__ void mvG(float* out, const float* __restrict__ Mg, const float* v, float* red) {
  const int t = threadIdx.x, r = t & 63, m0 = (t >> 6) << 2;
  float s = 0.f;
  #pragma unroll
  for (int k = 0; k < 4; ++k) s += Mg[(m0+k)*64 + r] * v[m0+k];
  red[t] = s;
  __syncthreads();
  if (t < 64) {
    float a = 0.f;
    #pragma unroll
    for (int q = 0; q < 16; ++q) a += red[q*64 + t];
    out[t] = a;
  }
  __syncthreads();
}

// out = (wa*Ma + wb*Mb) @ v, both global symmetric (ld 64), coalesced
__device__ __forceinline__ void mvGb(float* out, const float* __restrict__ Ma, const float* __restrict__ Mb,
                                     float wa, float wb, const float* v, float* red) {
  const int t = threadIdx.x, r = t & 63, m0 = (t >> 6) << 2;
  float sa = 0.f, sb = 0.f;
  #pragma unroll
  for (int k = 0; k < 4; ++k) {
    const float vv = v[m0+k];
    sa += Ma[(m0+k)*64 + r] * vv;
    sb += Mb[(m0+k)*64 + r] * vv;
  }
  red[t] = wa*sa + wb*sb;
  __syncthreads();
  if (t < 64) {
    float a = 0.f;
    #pragma unroll
    for (int q = 0; q < 16; ++q) a += red[q*64 + t];
    out[t] = a;
  }
  __syncthreads();
}

// jnp searchsorted-based linear interp on uniform grid g[i] = DT*i
__device__ __forceinline__ void interpIW(float t, int imax, int& i, float& w) {
  int ii = (int)floorf(t * 50.0f);
  ii = ii < 0 ? 0 : (ii > imax ? imax : ii);
  const float gi  = DT * (float)ii;
  const float gi1 = DT * (float)(ii + 1);
  float ww = (t - gi) / (gi1 - gi);
  ww = fminf(fmaxf(ww, 0.0f), 1.0f);
  i = ii; w = ww;
}

// ================= prep kernels =================
__global__ void kPrepA(const float* __restrict__ Rg, const float* __restrict__ Bg, float* __restrict__ ws) {
  __shared__ float M[8][17];
  __shared__ int spiv;
  const int t = threadIdx.x;   // 64 threads
  if (t < 8) {
    #pragma unroll
    for (int c = 0; c < 8; ++c) { M[t][c] = Rg[t*8 + c]; M[t][8 + c] = (t == c) ? 1.0f : 0.0f; }
  }
  __syncthreads();
  for (int col = 0; col < 8; ++col) {
    if (t == 0) {
      int piv = col; float best = fabsf(M[col][col]);
      for (int r = col + 1; r < 8; ++r) { const float a = fabsf(M[r][col]); if (a > best) { best = a; piv = r; } }
      spiv = piv;
    }
    __syncthreads();
    const int piv = spiv;
    if (piv != col && t < 16) { const float tmp = M[col][t]; M[col][t] = M[piv][t]; M[piv][t] = tmp; }
    __syncthreads();
    if (t < 16) { const float pv = M[col][col]; M[col][t] = M[col][t] / pv; }
    __syncthreads();
    if (t < 8 && t != col) {
      const float f = M[t][col];
      #pragma unroll
      for (int c = 0; c < 16; ++c) M[t][c] -= f * M[col][c];
    }
    __syncthreads();
  }
  if (t < 64) ws[O_RI + t] = M[t >> 3][8 + (t & 7)];
  __syncthreads();
  for (int o = t; o < 512; o += 64) {
    const int i = o >> 3, l = o & 7;
    float s = 0.f;
    #pragma unroll
    for (int p = 0; p < 8; ++p) s += Bg[i*8 + p] * M[p][8 + l];
    ws[O_BRI + o] = s;                     // (B@Ri)[i][l]
    const int p2 = o >> 6, j2 = o & 63;
    float s2 = 0.f;
    #pragma unroll
    for (int l2 = 0; l2 < 8; ++l2) s2 += M[p2][8 + l2] * Bg[j2*8 + l2];
    ws[O_RIBT + o] = s2;                   // (Ri@B^T)[p2][j2]
    ws[O_BT + o] = Bg[j2*8 + p2];          // B^T[p2][j2]
  }
}

__global__ void kPrepB(const float* __restrict__ Hg, float* __restrict__ ws, float* __restrict__ out) {
  const int total = 32768 + 8000;
  for (int idx = blockIdx.x * 256 + threadIdx.x; idx < total; idx += gridDim.x * 256) {
    if (idx < 32768) {
      const int n = idx >> 9, o = idx & 511, j = o >> 3, l = o & 7;
      ws[O_H1T + idx] = Hg[j*512 + n*8 + l];     // H1T[n][j*8+l] = H[j][n][l]
    } else {
      out[O_U0o + (idx - 32768)] = 0.0f;         // u_res[0] = 0
    }
  }
}

// ================= LQR Riccati: Ps backward =================
// field = (yB)Ri(yB)^T - M - M^T - Q with M = y@A   (y symmetric)
__global__ void __launch_bounds__(1024) kP(const float* __restrict__ Fg, const float* __restrict__ Qg,
                                           const float* __restrict__ Ag,
                                           const float* __restrict__ ws, float* __restrict__ Ps) {
  __shared__ float y0[64*LDM], acc[64*LDM], ytm[64*LDM], kb[64*LDM], Ms[64*LDM], As[64*LDM], Qs[64*LDM];
  __shared__ float BTs[512], Ris[64], yB[512], M2s[512], red[1024];
  const int t = threadIdx.x;
  { const int r = t >> 4, c0 = (t & 15) << 2;
    #pragma unroll
    for (int e = 0; e < 4; ++e) { const int c = c0 + e;
      y0[r*LDM + c] = Fg[r*64 + c];
      As[r*LDM + c] = Ag[r*64 + c];
      Qs[r*LDM + c] = Qg[r*64 + c];
    } }
  if (t < 512) BTs[t] = ws[O_BT + t];
  if (t < 64) Ris[t] = ws[O_RI + t];
  __syncthreads();
  { const int r = t >> 4, c0 = (t & 15) << 2;
    #pragma unroll
    for (int e = 0; e < 4; ++e) Ps[(size_t)NTS*4096 + r*64 + c0 + e] = y0[r*LDM + c0 + e]; }

  const float dt = -DT;
  const float c16 = dt / 6.0f, c13 = 2.0f * c16, c12 = 0.5f * dt;

  auto field = [&](const float* src) {
    // yB[i][l] = sum_m y[m][i] * BT[l][m]  (y sym; column reads conflict-free)
    { const int i = t & 63, l = (t >> 6) & 7, mb = (t >> 9) << 5;
      float s = 0.f;
      #pragma unroll 8
      for (int m = 0; m < 32; ++m) s += src[(mb+m)*LDM + i] * BTs[l*64 + mb + m];
      red[t] = s; }
    __syncthreads();
    if (t < 512) { const int i = t & 63, l = t >> 6; yB[i*8 + l] = red[t] + red[t + 512]; }
    __syncthreads();
    if (t < 512) {               // M2 = yB @ Ri
      const int i = t >> 3, l = t & 7;
      float s = 0.f;
      #pragma unroll
      for (int p = 0; p < 8; ++p) s += yB[i*8 + p] * Ris[p*8 + l];
      M2s[t] = s;
    }
    __syncthreads();
    mmNT<8, 8, 8, LDM, 0>(kb, M2s, yB);       // kbq = (yB)Ri(yB)^T
    mmNN<64, LDM, LDM, LDM, 0>(Ms, src, As);  // M = y@A
    __syncthreads();
  };

  for (int j = 0; j < NTS; ++j) {
    for (int st = 0; st < 4; ++st) {
      const float* src = (st == 0) ? y0 : ytm;
      field(src);
      EW4(I, J, IJ, {
        const float kv = kb[IJ] - Ms[IJ] - Ms[J*LDM + I] - Qs[IJ];
        if (st == 0)      { acc[IJ] = y0[IJ] + c16*kv; ytm[IJ] = y0[IJ] + c12*kv; }
        else if (st == 1) { acc[IJ] += c13*kv;         ytm[IJ] = y0[IJ] + c12*kv; }
        else if (st == 2) { acc[IJ] += c13*kv;         ytm[IJ] = y0[IJ] + dt*kv;  }
        else              { y0[IJ] = acc[IJ] + c16*kv; }
      });
      __syncthreads();
    }
    { const int r = t >> 4, c0 = (t & 15) << 2;
      float4* dst = (float4*)&Ps[(size_t)(NTS-1-j)*4096 + r*64 + c0];
      *dst = make_float4(y0[r*LDM+c0], y0[r*LDM+c0+1], y0[r*LDM+c0+2], y0[r*LDM+c0+3]); }
    __syncthreads();
  }
}

// ================= iteration 0: x' = A x =================
__global__ void __launch_bounds__(1024) kX0(const float* __restrict__ Ag, const float* __restrict__ x0g,
                                            float* __restrict__ out) {
  __shared__ float As[64*LDM], xv[64], xt[64], ks[4][64], red[1024];
  const int t = threadIdx.x;
  { const int r = t >> 4, c0 = (t & 15) << 2;
    #pragma unroll
    for (int e = 0; e < 4; ++e) As[r*LDM + c0 + e] = Ag[r*64 + c0 + e]; }
  if (t < 64) xv[t] = x0g[t];
  __syncthreads();
  for (int j = 0; j < NTS; ++j) {
    if (t < 64) out[O_X0o + j*64 + t] = xv[t];
    __syncthreads();
    if (j == NTS - 1) break;
    for (int st = 0; st < 4; ++st) {
      const float* src = (st == 0) ? xv : xt;
      mvL(ks[st], As, src, red);
      if (t < 64 && st < 3) xt[t] = xv[t] + (st == 2 ? DT : 0.01f) * ks[st][t];
      __syncthreads();
    }
    if (t < 64) xv[t] += (DT/6.0f) * (ks[0][t] + 2.0f*ks[1][t] + 2.0f*ks[2][t] + ks[3][t]);
    __syncthreads();
  }
}

// ================= iteration 1: LQR sweep + u1 =================
__global__ void __launch_bounds__(1024) kXgrid(const float* __restrict__ Ag, const float* __restrict__ Bg,
                                               const float* __restrict__ x0g,
                                               float* __restrict__ ws, float* __restrict__ out) {
  __shared__ float As[64*LDM], Bs[512], RiBTs[512];
  __shared__ float xv[64], xt[64], ks[4][64], pv[64], g8[8], red[1024];
  const int t = threadIdx.x;
  const float* Ps = ws + O_PS;
  { const int r = t >> 4, c0 = (t & 15) << 2;
    #pragma unroll
    for (int e = 0; e < 4; ++e) As[r*LDM + c0 + e] = Ag[r*64 + c0 + e]; }
  if (t < 512) { Bs[t] = Bg[t]; RiBTs[t] = ws[O_RIBT + t]; }
  if (t < 64) xv[t] = x0g[t];
  __syncthreads();

  auto field = [&](float tau, const float* src, float* kout) {
    int i; float w; interpIW(tau, NTS - 1, i, w);
    mvGb(pv, Ps + (size_t)i*4096, Ps + (size_t)(i+1)*4096, 1.0f - w, w, src, red);
    { const int wv = t >> 6, m = t & 63;
      if (wv < 8) { const float rr = wred64(RiBTs[wv*64 + m] * pv[m]); if (m == 0) g8[wv] = rr; } }
    mvL(kout, As, src, red);            // internal barriers also publish g8
    if (t < 64) {
      float s = 0.f;
      #pragma unroll
      for (int p = 0; p < 8; ++p) s += Bs[t*8 + p] * g8[p];
      kout[t] -= s;
    }
    __syncthreads();
  };

  for (int j = 0; j < NTS; ++j) {
    if (t < 64) { out[O_X1o + j*64 + t] = xv[t]; ws[O_XG + j*64 + t] = xv[t]; }
    __syncthreads();
    mvG(pv, Ps + (size_t)j*4096, xv, red);           // exact-grid Ps[j]@x for u1
    if (t < 8) {
      float s = 0.f;
      #pragma unroll 8
      for (int m = 0; m < 64; ++m) s += RiBTs[t*64 + m] * pv[m];
      out[O_U1o + j*8 + t] = -s;
    }
    __syncthreads();
    if (j == NTS - 1) break;
    const float tj = DT * (float)j;
    for (int st = 0; st < 4; ++st) {
      const float tau = tj + ((st == 0) ? 0.0f : (st == 3) ? DT : 0.01f);
      const float* src = (st == 0) ? xv : xt;
      field(tau, src, ks[st]);
      if (t < 64 && st < 3) xt[t] = xv[t] + (st == 2 ? DT : 0.01f) * ks[st][t];
      __syncthreads();
    }
    if (t < 64) xv[t] += (DT/6.0f) * (ks[0][t] + 2.0f*ks[1][t] + 2.0f*ks[2][t] + ks[3][t]);
    __syncthreads();
  }
}

// ================= x_k1: forward sweep with A_k =================
__global__ void __launch_bounds__(1024) kXk1(const float* __restrict__ Ag, const float* __restrict__ Bg,
                                             const float* __restrict__ Hg, const float* __restrict__ x0g,
                                             float* __restrict__ ws) {
  __shared__ float Atil[64*LDM];
  __shared__ float RiBTs[512], BRis[512], Ris[64];
  __shared__ float Hx[512], Bt[512], BtRi[512], G[512];
  __shared__ float xv[64], xt[64], xk[64], pk[64], pv[64], sv[64];
  __shared__ float ks[4][64], e1[8], e2[8], e3[8], e8v[8], w8[8], red[1024];
  __shared__ int ci; __shared__ float cw;
  const int t = threadIdx.x;
  const float* Ps = ws + O_PS;
  const float* xg = ws + O_XG;
  if (t < 512) { RiBTs[t] = ws[O_RIBT + t]; BRis[t] = ws[O_BRI + t]; }
  if (t < 64) { Ris[t] = ws[O_RI + t]; xv[t] = x0g[t]; }
  __syncthreads();

  auto build = [&](float tau) {
    int i, ix; float w, wx;
    interpIW(tau, NTS - 1, i, w);
    interpIW(tau, NTS - 2, ix, wx);
    if (t == 0) { ci = i; cw = w; }
    if (t < 64) xk[t] = (1.0f - wx) * xg[ix*64 + t] + wx * xg[(ix+1)*64 + t];
    __syncthreads();
    mvGb(pk, Ps + (size_t)i*4096, Ps + (size_t)(i+1)*4096, 1.0f - w, w, xk, red);
    // Hx (waves 0-7, via H1T coalesced) and G (waves 8-15, via Hg natural-coalesced)
    if (t < 512) {
      const int o = t; float s = 0.f;
      #pragma unroll 8
      for (int n = 0; n < 64; ++n) s += ws[O_H1T + n*512 + o] * xk[n];
      Hx[o] = s; Bt[o] = Bg[o] + s;
    } else {
      const int o = t - 512; float s = 0.f;
      #pragma unroll 8
      for (int m = 0; m < 64; ++m) s += Hg[m*512 + o] * pk[m];
      G[o] = s;
    }
    __syncthreads();
    { const int wv = t >> 6, m = t & 63;                  // e8v = B^T pk (wave reduce)
      if (wv < 8) { const float rr = wred64(ws[O_BT + wv*64 + m] * pk[m]); if (m == 0) e8v[wv] = rr; } }
    __syncthreads();
    if (t < 8) {
      float s = 0.f;
      #pragma unroll
      for (int l = 0; l < 8; ++l) s += Ris[t*8 + l] * e8v[l];
      w8[t] = s;
    }
    __syncthreads();
    if (t < 512) {                                        // BtRi = Bt @ Ri
      const int i2 = t >> 3, l = t & 7;
      float s = 0.f;
      #pragma unroll
      for (int p = 0; p < 8; ++p) s += Bt[i2*8 + p] * Ris[p*8 + l];
      BtRi[t] = s;
    }
    EW4(I, J, IJ, {                                       // T1 = H . w8 (coalesced Hg)
      const float4 h0 = *(const float4*)&Hg[I*512 + J*8];
      const float4 h1 = *(const float4*)&Hg[I*512 + J*8 + 4];
      Atil[IJ] = h0.x*w8[0]+h0.y*w8[1]+h0.z*w8[2]+h0.w*w8[3]
               + h1.x*w8[4]+h1.y*w8[5]+h1.z*w8[6]+h1.w*w8[7];
    });
    __syncthreads();
    mmNT<8, 8, 8, LDM, 1>(Atil, BRis, G);                 // += BRi@G^T
    __syncthreads();
    EW4(I, J, IJ, { Atil[IJ] = Ag[I*64 + J] - 0.5f*Atil[IJ]; });
    __syncthreads();
  };

  auto fieldK = [&](const float* src, float* kout) {
    mvGb(pv, Ps + (size_t)ci*4096, Ps + (size_t)(ci+1)*4096, 1.0f - cw, cw, src, red);
    { const int wv = t >> 6, m = t & 63;
      const float c1 = (wv < 8) ? Bt[m*8 + wv] * pv[m] : RiBTs[(wv-8)*64 + m] * pv[m];
      const float r1 = wred64(c1);
      if (m == 0) { if (wv < 8) e1[wv] = r1; else e2[wv-8] = r1; }
      if (wv < 8) { const float r3 = wred64(Hx[m*8 + wv] * pv[m]); if (m == 0) e3[wv] = r3; } }
    __syncthreads();
    if (t < 64) {                                         // sv = S @ (P y)
      float s1 = 0.f, s2 = 0.f, s3 = 0.f;
      #pragma unroll
      for (int p = 0; p < 8; ++p) {
        s1 += BtRi[t*8 + p] * e1[p];
        s2 += Hx[t*8 + p]   * e2[p];
        s3 += BRis[t*8 + p] * e3[p];
      }
      sv[t] = s1 - 0.5f*(s2 + s3);
    }
    mvL(kout, Atil, src, red);
    if (t < 64) kout[t] -= sv[t];
    __syncthreads();
  };

  for (int j = 0; j < NTS; ++j) {
    if (t < 64) ws[O_XK1 + j*64 + t] = xv[t];
    __syncthreads();
    if (j == NTS - 1) break;
    const float tj = DT * (float)j;
    for (int st = 0; st < 4; ++st) {
      if (st != 2) build(tj + ((st == 0) ? 0.0f : (st == 3) ? DT : 0.01f));
      const float* src = (st == 0) ? xv : xt;
      fieldK(src, ks[st]);
      if (t < 64 && st < 3) xt[t] = xv[t] + (st == 2 ? DT : 0.01f) * ks[st][t];
      __syncthreads();
    }
    if (t < 64) xv[t] += (DT/6.0f) * (ks[0][t] + 2.0f*ks[1][t] + 2.0f*ks[2][t] + ks[3][t]);
    __syncthreads();
  }
}

// ================= P_k1: backward matrix Riccati with A_k, Q_k =================
__global__ void __launch_bounds__(1024) kPk1(const float* __restrict__ Fg, const float* __restrict__ Ag,
                                             const float* __restrict__ Bg, const float* __restrict__ Hg,
                                             float* __restrict__ ws) {
  __shared__ float y0[64*LDM], acc[64*LDM], ytm[64*LDM], kb[64*LDM];
  __shared__ float Pc[64*LDM], Ss[64*LDM], SP[64*LDM], Akt[64*LDM];
  __shared__ float RiBTs[512], BRis[512], Ris[64];
  __shared__ float Hx[512], Bt[512], BtRi[512], G[512], GRi[512];
  __shared__ float xk[64], pk[64], e8v[8], w8[8], red[1024];
  const int t = threadIdx.x;
  const float* Psg = ws + O_PS;
  const float* xg = ws + O_XG;
  float* Pk1g = ws + O_PK1;
  { const int r = t >> 4, c0 = (t & 15) << 2;
    #pragma unroll
    for (int e = 0; e < 4; ++e) y0[r*LDM + c0 + e] = Fg[r*64 + c0 + e]; }
  if (t < 512) { RiBTs[t] = ws[O_RIBT + t]; BRis[t] = ws[O_BRI + t]; }
  if (t < 64) Ris[t] = ws[O_RI + t];
  __syncthreads();

  const float dt = -DT;
  const float c16 = dt / 6.0f, c13 = 2.0f * c16, c12 = 0.5f * dt;

  auto build = [&](float tau) {
    int i, ix; float w, wx;
    interpIW(tau, NTS - 1, i, w);
    interpIW(tau, NTS - 2, ix, wx);
    if (t < 64) xk[t] = (1.0f - wx) * xg[ix*64 + t] + wx * xg[(ix+1)*64 + t];
    { const int r = t >> 4, c0 = (t & 15) << 2;               // Pc = blend (coalesced f4)
      const float4 a = *(const float4*)&Psg[(size_t)i*4096 + r*64 + c0];
      const float4 b = *(const float4*)&Psg[(size_t)(i+1)*4096 + r*64 + c0];
      const float wa = 1.0f - w;
      float* d = &Pc[r*LDM + c0];
      d[0] = wa*a.x + w*b.x; d[1] = wa*a.y + w*b.y; d[2] = wa*a.z + w*b.z; d[3] = wa*a.w + w*b.w; }
    __syncthreads();
    mvLsym(pk, Pc, xk, red);                                  // pk = Pc@xk (Pc sym)
    if (t < 512) {                                            // Hx via H1T; Bt
      const int o = t; float s = 0.f;
      #pragma unroll 8
      for (int n = 0; n < 64; ++n) s += ws[O_H1T + n*512 + o] * xk[n];
      Hx[o] = s; Bt[o] = Bg[o] + s;
    } else {                                                  // G via Hg (natural coalesced)
      const int o = t - 512; float s = 0.f;
      #pragma unroll 8
      for (int m = 0; m < 64; ++m) s += Hg[m*512 + o] * pk[m];
      G[o] = s;
    }
    __syncthreads();
    { const int wv = t >> 6, m = t & 63;                      // e8v = B^T pk
      if (wv < 8) { const float rr = wred64(ws[O_BT + wv*64 + m] * pk[m]); if (m == 0) e8v[wv] = rr; } }
    __syncthreads();
    if (t < 8) {
      float s = 0.f;
      #pragma unroll
      for (int l = 0; l < 8; ++l) s += Ris[t*8 + l] * e8v[l];
      w8[t] = s;
    }
    __syncthreads();
    if (t < 512) {                                            // BtRi, GRi
      const int i2 = t >> 3, l = t & 7;
      float s1 = 0.f, s2 = 0.f;
      #pragma unroll
      for (int p = 0; p < 8; ++p) { s1 += Bt[i2*8 + p] * Ris[p*8 + l]; s2 += G[i2*8 + p] * Ris[p*8 + l]; }
      BtRi[t] = s1; GRi[t] = s2;
    }
    EW4(I, J, IJ, {                                           // Akt = T1 = H . w8
      const float4 h0 = *(const float4*)&Hg[I*512 + J*8];
      const float4 h1 = *(const float4*)&Hg[I*512 + J*8 + 4];
      Akt[IJ] = h0.x*w8[0]+h0.y*w8[1]+h0.z*w8[2]+h0.w*w8[3]
              + h1.x*w8[4]+h1.y*w8[5]+h1.z*w8[6]+h1.w*w8[7];
    });
    __syncthreads();
    mmNT<8, 8, 8, LDM, 0>(Ss, BtRi, Bt);                      // Bt Ri Bt^T
    mmNN<8, 8, 64, LDM, 0>(kb, Hx, RiBTs);                    // Hx @ RiB^T
    __syncthreads();
    EW4(I, J, IJ, { Ss[IJ] = Ss[IJ] - 0.5f*(kb[IJ] + kb[J*LDM + I]); });  // S
    __syncthreads();
    mmNN<64, LDM, LDM, LDM, 0>(SP, Ss, Pc);                   // SP = S@P
    __syncthreads();
    mmNN<64, LDM, LDM, LDM, 0>(kb, Pc, SP);                   // kb = P S P
    mmNT<8, 8, 8, LDM, 0>(Ss, GRi, G);                        // Ss = M = G Ri G^T
    __syncthreads();
    EW4(I, J, IJ, { Pc[IJ] = Ss[IJ] + Ss[J*LDM + I] - kb[IJ]; });  // Q_k (reuse Pc)
    __syncthreads();
    mmNT<8, 8, 8, LDM, 1>(Akt, BRis, G);                      // T1 += BRi@G^T
    __syncthreads();
    EW4(I, J, IJ, { Akt[IJ] = Ag[I*64 + J] - 0.5f*Akt[IJ] - SP[IJ]; });   // A_k
    __syncthreads();
  };

  for (int j = 0; j < NTS; ++j) {
    const float tj = 20.0f - DT * (float)j;
    for (int st = 0; st < 4; ++st) {
      if (st != 2) build(tj - ((st == 0) ? 0.0f : (st == 3) ? DT : 0.01f));
      const float* src = (st == 0) ? y0 : ytm;
      mmNN<64, LDM, LDM, LDM, 0>(kb, src, Akt);               // M = y@A_k (y sym)
      __syncthreads();
      EW4(I, J, IJ, {
        const float kv = -(kb[IJ] + kb[J*LDM + I] + Pc[IJ]);  // -yA_k - A_k^T y - Q_k
        if (st == 0)      { acc[IJ] = y0[IJ] + c16*kv; ytm[IJ] = y0[IJ] + c12*kv; }
        else if (st == 1) { acc[IJ] += c13*kv;         ytm[IJ] = y0[IJ] + c12*kv; }
        else if (st == 2) { acc[IJ] += c13*kv;         ytm[IJ] = y0[IJ] + dt*kv;  }
        else              { y0[IJ] = acc[IJ] + c16*kv; }
      });
      __syncthreads();
    }
    { const int r = t >> 4, c0 = (t & 15) << 2;
      float4* dst = (float4*)&Pk1g[(size_t)(NTS-1-j)*4096 + r*64 + c0];
      *dst = make_float4(y0[r*LDM+c0], y0[r*LDM+c0+1], y0[r*LDM+c0+2], y0[r*LDM+c0+3]); }
    __syncthreads();
  }
}

// ================= u_grid (parallel over time) =================
__global__ void __launch_bounds__(256) kUgrid(const float* __restrict__ ws, float* __restrict__ out) {
  const int j = blockIdx.x, t = threadIdx.x;
  __shared__ float xvj[64], x1[64], vv[64], hxv[512], w8s[8], red[256];
  if (t < 64) { xvj[t] = ws[O_XG + j*64 + t]; x1[t] = ws[O_XK1 + j*64 + t]; }
  __syncthreads();
  { const int r = t & 63, m0 = (t >> 6) << 4;          // vv = Pk1[j]@x1 (sym, coalesced)
    const float* Mg = ws + O_PK1 + (size_t)j*4096;
    float s = 0.f;
    #pragma unroll
    for (int m = 0; m < 16; ++m) s += Mg[(m0+m)*64 + r] * x1[m0+m];
    red[t] = s; }
  __syncthreads();
  if (t < 64) vv[t] = (red[t] + red[64+t]) + (red[128+t] + red[192+t]);
  __syncthreads();
  for (int o = t; o < 512; o += 256) {
    float s = 0.f;
    #pragma unroll 8
    for (int n = 0; n < 64; ++n) s += ws[O_H1T + n*512 + o] * xvj[n];
    hxv[o] = vv[o >> 3] * s;
  }
  __syncthreads();
  if (t < 8) {
    float s = 0.f;
    #pragma unroll 8
    for (int j2 = 0; j2 < 64; ++j2) s += hxv[j2*8 + t];
    w8s[t] = s;
  }
  __syncthreads();
  if (t < 8) {
    float s = 0.f;
    #pragma unroll
    for (int l = 0; l < 8; ++l) s += ws[O_RI + t*8 + l] * w8s[l];
    out[O_U2o + j*8 + t] = -s;                         // u = -Ri @ w
  }
}

// ================= x_eval: forward sweep with A_k_tilde + B_k_tilde u =================
__global__ void __launch_bounds__(1024) kXeval(const float* __restrict__ Ag, const float* __restrict__ Bg,
                                               const float* __restrict__ Hg, const float* __restrict__ x0g,
                                               float* __restrict__ ws, float* __restrict__ out) {
  __shared__ float Atil[64*LDM];
  __shared__ float BRis[512], Ris[64];
  __shared__ float Hx[512], Bt[512], G[512];
  __shared__ float xv[64], xt[64], xk[64], pk[64], bu[64];
  __shared__ float ks[4][64], e8v[8], w8[8], uu8[8], red[1024];
  const int t = threadIdx.x;
  const float* Ps = ws + O_PS;
  const float* xg = ws + O_XG;
  const float* Ug = out + O_U2o;
  if (t < 512) BRis[t] = ws[O_BRI + t];
  if (t < 64) { Ris[t] = ws[O_RI + t]; xv[t] = x0g[t]; }
  __syncthreads();

  auto build = [&](float tau) {
    int i, ix; float w, wx;
    interpIW(tau, NTS - 1, i, w);
    interpIW(tau, NTS - 2, ix, wx);
    if (t < 64) xk[t] = (1.0f - wx) * xg[ix*64 + t] + wx * xg[(ix+1)*64 + t];
    __syncthreads();
    mvGb(pk, Ps + (size_t)i*4096, Ps + (size_t)(i+1)*4096, 1.0f - w, w, xk, red);
    if (t < 512) {
      const int o = t; float s = 0.f;
      #pragma unroll 8
      for (int n = 0; n < 64; ++n) s += ws[O_H1T + n*512 + o] * xk[n];
      Hx[o] = s; Bt[o] = Bg[o] + s;
    } else {
      const int o = t - 512; float s = 0.f;
      #pragma unroll 8
      for (int m = 0; m < 64; ++m) s += Hg[m*512 + o] * pk[m];
      G[o] = s;
    }
    __syncthreads();
    { const int wv = t >> 6, m = t & 63;
      if (wv < 8) { const float rr = wred64(ws[O_BT + wv*64 + m] * pk[m]); if (m == 0) e8v[wv] = rr; } }
    __syncthreads();
    if (t < 8) {
      float s = 0.f;
      #pragma unroll
      for (int l = 0; l < 8; ++l) s += Ris[t*8 + l] * e8v[l];
      w8[t] = s;
    } else if (t < 16) {
      const int p = t - 8;
      uu8[p] = (1.0f - wx) * Ug[ix*8 + p] + wx * Ug[(ix+1)*8 + p];
    }
    __syncthreads();
    EW4(I, J, IJ, {
      const float4 h0 = *(const float4*)&Hg[I*512 + J*8];
      const float4 h1 = *(const float4*)&Hg[I*512 + J*8 + 4];
      Atil[IJ] = h0.x*w8[0]+h0.y*w8[1]+h0.z*w8[2]+h0.w*w8[3]
               + h1.x*w8[4]+h1.y*w8[5]+h1.z*w8[6]+h1.w*w8[7];
    });
    __syncthreads();
    mmNT<8, 8, 8, LDM, 1>(Atil, BRis, G);
    __syncthreads();
    EW4(I, J, IJ, { Atil[IJ] = Ag[I*64 + J] - 0.5f*Atil[IJ]; });
    if (t < 64) {
      float s = 0.f;
      #pragma unroll
      for (int l = 0; l < 8; ++l) s += Bt[t*8 + l] * uu8[l];   // B_k_tilde @ u
      bu[t] = s;
    }
    __syncthreads();
  };

  for (int j = 0; j < NTS; ++j) {
    if (t < 64) out[O_X2o + j*64 + t] = xv[t];
    __syncthreads();
    if (j == NTS - 1) break;
    const float tj = DT * (float)j;
    for (int st = 0; st < 4; ++st) {
      if (st != 2) build(tj + ((st == 0) ? 0.0f : (st == 3) ? DT : 0.01f));
      const float* src = (st == 0) ? xv : xt;
      mvL(ks[st], Atil, src, red);
      if (t < 64) ks[st][t] += bu[t];
      __syncthreads();
      if (t < 64 && st < 3) xt[t] = xv[t] + (st == 2 ? DT : 0.01f) * ks[st][t];
      __syncthreads();
    }
    if (t < 64) xv[t] += (DT/6.0f) * (ks[0][t] + 2.0f*ks[1][t] + 2.0f*ks[2][t] + ks[3][t]);
    __syncthreads();
  }
}

// ================= launch =================
extern "C" void kernel_launch(void* const* d_in, const int* in_sizes, int n_in,
                              void* d_out, int out_size, void* d_ws, size_t ws_size,
                              hipStream_t stream) {
  const float* F  = (const float*)d_in[0];
  const float* Q  = (const float*)d_in[1];
  const float* R  = (const float*)d_in[2];
  const float* A  = (const float*)d_in[3];
  const float* B  = (const float*)d_in[4];
  const float* H  = (const float*)d_in[5];
  const float* x0 = (const float*)d_in[6];
  float* out = (float*)d_out;
  float* ws  = (float*)d_ws;
  (void)in_sizes; (void)n_in; (void)out_size; (void)ws_size;  // needs ws_size >= ~33.5 MB

  kPrepA<<<1, 64, 0, stream>>>(R, B, ws);
  kPrepB<<<64, 256, 0, stream>>>(H, ws, out);
  kP<<<1, 1024, 0, stream>>>(F, Q, A, ws, ws + O_PS);
  kX0<<<1, 1024, 0, stream>>>(A, x0, out);
  kXgrid<<<1, 1024, 0, stream>>>(A, B, x0, ws, out);
  kXk1<<<1, 1024, 0, stream>>>(A, B, H, x0, ws);
  kPk1<<<1, 1024, 0, stream>>>(F, A, B, H, ws);
  kUgrid<<<NTS, 256, 0, stream>>>(ws, out);
  kXeval<<<1, 1024, 0, stream>>>(A, B, H, x0, ws, out);
}